// Round 7
// baseline (539.047 us; speedup 1.0000x reference)
//
#include <hip/hip_runtime.h>
#include <hip/hip_bf16.h>

// MoE top-1 (GShard) for MI355X.
// S=8192 tokens, m=1024, E=8, ffn=4096, C=1024.
// R9: true m201-style 8-phase schedule on R8's 256x256/BK=64 geometry.
//     Per 2 K-tiles: 8 phases of {ds_read subtile | stage 1 half-tile |
//     barrier | lgkm(0) | setprio(1) 16xMFMA setprio(0) | barrier}.
//     Half-tile slot schedule (read-liveness-derived): ph0-2 stage tile b's
//     Al/Bh/Ah, ph3 Bl(a+2)+vmcnt(2), ph4-6 Al/Bh/Ah(a+2), ph7 Bl(b+2)+vmcnt(2).
//     vmcnt never 0 mid-loop (once at tail). R8 landed at the documented
//     2-phase plateau (589 TF ~ m230's 682); 8ph+T5 is the cataloged escape.

#define NTOK 8192
#define DM   1024
#define NE   8
#define NF   4096
#define CAP  1024

typedef __bf16 bf16x8 __attribute__((ext_vector_type(8)));
typedef float  f32x4  __attribute__((ext_vector_type(4)));
typedef unsigned short us8v __attribute__((ext_vector_type(8)));

__device__ __forceinline__ unsigned short f2bf(float f) {
    union { float f; unsigned int u; } v; v.f = f;
    unsigned int u = v.u;
    return (unsigned short)((u + 0x7FFFu + ((u >> 16) & 1u)) >> 16); // RNE
}

__device__ __forceinline__ void async_cp16(const unsigned short* g, unsigned short* l) {
    __builtin_amdgcn_global_load_lds(
        (const __attribute__((address_space(1))) void*)g,
        (__attribute__((address_space(3))) void*)l, 16, 0, 0);
}

// ---------------- gating: one wave per token ----------------
__global__ __launch_bounds__(256) void gate_kernel(
    const float* __restrict__ x, const float* __restrict__ wg,
    int* __restrict__ eid, float* __restrict__ gatev)
{
    int wave = threadIdx.x >> 6;
    int lane = threadIdx.x & 63;
    int t = blockIdx.x * 4 + wave;
    const float4* xr4 = (const float4*)(x + (size_t)t * DM);
    float acc[NE];
#pragma unroll
    for (int e = 0; e < NE; ++e) acc[e] = 0.f;
#pragma unroll
    for (int it = 0; it < 4; ++it) {
        int k4 = lane + it * 64;
        float4 xv = xr4[k4];
        float xc[4] = {xv.x, xv.y, xv.z, xv.w};
#pragma unroll
        for (int c = 0; c < 4; ++c) {
            const float4* wr = (const float4*)(wg + (size_t)(k4 * 4 + c) * NE);
            float4 w0 = wr[0], w1 = wr[1];
            acc[0] += xc[c] * w0.x; acc[1] += xc[c] * w0.y;
            acc[2] += xc[c] * w0.z; acc[3] += xc[c] * w0.w;
            acc[4] += xc[c] * w1.x; acc[5] += xc[c] * w1.y;
            acc[6] += xc[c] * w1.z; acc[7] += xc[c] * w1.w;
        }
    }
#pragma unroll
    for (int off = 32; off >= 1; off >>= 1) {
#pragma unroll
        for (int e = 0; e < NE; ++e) acc[e] += __shfl_xor(acc[e], off, 64);
    }
    if (lane == 0) {
        int best = 0; float bm = acc[0];
#pragma unroll
        for (int e = 1; e < NE; ++e) if (acc[e] > bm) { bm = acc[e]; best = e; } // first-max like jnp.argmax
        float ssum = 0.f;
#pragma unroll
        for (int e = 0; e < NE; ++e) ssum += __expf(acc[e] - bm);
        eid[t] = best;
        gatev[t] = 1.0f / ssum;  // softmax prob of argmax expert
    }
}

// ---------------- ordered per-expert cumsum, wave-shuffle scan ----------------
__global__ __launch_bounds__(1024) void scan_kernel(
    const int* __restrict__ eid, int* __restrict__ slot_token)
{
    __shared__ int wtot[16][NE];
    int tid = threadIdx.x;
    int lane = tid & 63, wv = tid >> 6;
#pragma unroll
    for (int i = 0; i < 8; ++i) slot_token[tid + i * 1024] = -1;

    int el[8];
    int cnt[NE];
#pragma unroll
    for (int e = 0; e < NE; ++e) cnt[e] = 0;
#pragma unroll
    for (int i = 0; i < 8; ++i) {
        int e = eid[tid * 8 + i];
        el[i] = e;
        cnt[e]++;
    }
    int incl[NE];
#pragma unroll
    for (int e = 0; e < NE; ++e) incl[e] = cnt[e];
#pragma unroll
    for (int off = 1; off <= 32; off <<= 1) {
#pragma unroll
        for (int e = 0; e < NE; ++e) {
            int v = __shfl_up(incl[e], off, 64);
            if (lane >= off) incl[e] += v;
        }
    }
    if (lane == 63) {
#pragma unroll
        for (int e = 0; e < NE; ++e) wtot[wv][e] = incl[e];
    }
    __syncthreads();
    int base[NE];
#pragma unroll
    for (int e = 0; e < NE; ++e) {
        int s = 0;
        for (int w = 0; w < 16; ++w) s += (w < wv) ? wtot[w][e] : 0;
        base[e] = s + incl[e] - cnt[e];   // exclusive prefix for this thread
    }
#pragma unroll
    for (int i = 0; i < 8; ++i) {
        int e = el[i];
        int loc = base[e]++;
        if (loc < CAP) slot_token[e * CAP + loc] = tid * 8 + i;
    }
}

// ---------------- f32 [E][K][N] -> bf16 [E][N][K] convert+transpose ----------------
template<int K, int N>
__global__ __launch_bounds__(256) void convT_kernel(
    const float* __restrict__ W, unsigned short* __restrict__ WT)
{
    __shared__ unsigned short tile[64][72];
    int e = blockIdx.z;
    int k0 = blockIdx.y * 64, n0 = blockIdx.x * 64;
    const float* Wp = W + (size_t)e * K * N;
    unsigned short* WTp = WT + (size_t)e * K * N;
    int tid = threadIdx.x;
    int cn = (tid & 15) * 4;
    int rk = tid >> 4;
#pragma unroll
    for (int i = 0; i < 4; ++i) {
        int k = rk + i * 16;
        float4 v = *(const float4*)(Wp + (size_t)(k0 + k) * N + n0 + cn);
        tile[cn + 0][k] = f2bf(v.x);
        tile[cn + 1][k] = f2bf(v.y);
        tile[cn + 2][k] = f2bf(v.z);
        tile[cn + 3][k] = f2bf(v.w);
    }
    __syncthreads();
    int ck = (tid & 7) * 8;
    int rn = tid >> 3;
#pragma unroll
    for (int i = 0; i < 2; ++i) {
        int n = rn + i * 32;
        us8v o;
#pragma unroll
        for (int c = 0; c < 8; ++c) o[c] = tile[n][ck + c];
        *(us8v*)(WTp + (size_t)(n0 + n) * K + k0 + ck) = o;
    }
}

// ---------------- gather dispatched tokens into bf16 [E*C][m] ----------------
__global__ __launch_bounds__(256) void gather_kernel(
    const float* __restrict__ x, const int* __restrict__ slot_token,
    unsigned short* __restrict__ Xd)
{
    int tid = threadIdx.x;
    int local = tid & 127;
    int slot = blockIdx.x * 2 + (tid >> 7);
    int t = slot_token[slot];
    int c = local * 8;
    us8v o;
    if (t >= 0) {
        const float4* p = (const float4*)(x + (size_t)t * DM + c);
        float4 v0 = p[0], v1 = p[1];
        o[0] = f2bf(v0.x); o[1] = f2bf(v0.y); o[2] = f2bf(v0.z); o[3] = f2bf(v0.w);
        o[4] = f2bf(v1.x); o[5] = f2bf(v1.y); o[6] = f2bf(v1.z); o[7] = f2bf(v1.w);
    } else {
#pragma unroll
        for (int c8 = 0; c8 < 8; ++c8) o[c8] = 0;
    }
    *(us8v*)(Xd + (size_t)slot * DM + c) = o;
}

// ======== 256x256 / BK=64 / 8-wave / 8-phase core (m201 port) ========
// LDS (shorts): A tiles at 0 (2 x 16384), B tiles at 32768 (2 x 16384). 128KB.
// T2 swizzle: byte ^= (row&7)<<4, pre-swizzled global source + swizzled read.
// Half-tile = 128 rows x 64k = 16KB = 2 gload_lds/thread.
// Phase = {ds_read subtile | stage 1 half | barrier | lgkm0 | prio1 16MFMA prio0 | barrier}
// vmcnt(2) at ph3/ph7 only (tail: vmcnt(0) at last ph3).
template<int KLEN, int LD>
__device__ __forceinline__ void gemm_core8p(
    const unsigned short* __restrict__ Ab, const unsigned short* __restrict__ Bb,
    unsigned short* sm, f32x4 acc[8][4])
{
    int tid = threadIdx.x;              // 0..511
    int wave = tid >> 6, lane = tid & 63;
    int wr = (wave >> 2) * 128;         // M-half
    int wc = (wave & 3) * 64;           // N-quarter
#pragma unroll
    for (int i = 0; i < 8; ++i)
#pragma unroll
        for (int j = 0; j < 4; ++j) acc[i][j] = (f32x4){0.f, 0.f, 0.f, 0.f};

    int g_row = tid >> 3;               // 0..63
    int g_colb = (tid & 7) * 16;        // byte col in 128B row
    int lxor = (lane & 7) << 4;
    int l15 = lane & 15;
    int khi = (lane >> 4) * 16;         // byte offset within 64B kk-block

    constexpr int NT = KLEN / 64;
    constexpr int NI = NT / 2;

#define STG(OPBASE, SRC, T, H)                                                 \
    {                                                                          \
        unsigned short* dst_ = sm + (OPBASE) + ((T) & 1) * 16384 + (H) * 8192; \
        _Pragma("unroll")                                                      \
        for (int s_ = 0; s_ < 2; ++s_) {                                       \
            int row_ = (H) * 128 + s_ * 64 + g_row;                            \
            int sc_ = (g_colb ^ ((row_ & 7) << 4)) >> 1;                       \
            async_cp16(SRC + (size_t)row_ * LD + (T) * 64 + sc_,               \
                       dst_ + s_ * 4096 + tid * 8);                            \
        }                                                                      \
    }
#define RDA(AF, T, I0, KS)                                                     \
    {                                                                          \
        const unsigned short* Ac_ = sm + ((T) & 1) * 16384;                    \
        int xo_ = (((KS) * 64 + khi) ^ lxor) >> 1;                             \
        _Pragma("unroll")                                                      \
        for (int i_ = 0; i_ < 4; ++i_) {                                       \
            int r_ = wr + ((I0) + i_) * 16 + l15;                              \
            AF[i_] = *(const bf16x8*)(Ac_ + r_ * 64 + xo_);                    \
        }                                                                      \
    }
#define RDB(BF, T, KS)                                                         \
    {                                                                          \
        const unsigned short* Bc_ = sm + 32768 + ((T) & 1) * 16384;            \
        int xo_ = (((KS) * 64 + khi) ^ lxor) >> 1;                             \
        _Pragma("unroll")                                                      \
        for (int j_ = 0; j_ < 4; ++j_) {                                       \
            int c_ = wc + j_ * 16 + l15;                                       \
            BF[j_] = *(const bf16x8*)(Bc_ + c_ * 64 + xo_);                    \
        }                                                                      \
    }
#define MM16(I0, AF, BF)                                                       \
    _Pragma("unroll")                                                          \
    for (int i_ = 0; i_ < 4; ++i_)                                             \
        _Pragma("unroll")                                                      \
        for (int j_ = 0; j_ < 4; ++j_)                                         \
            acc[(I0) + i_][j_] = __builtin_amdgcn_mfma_f32_16x16x32_bf16(      \
                AF[i_], BF[j_], acc[(I0) + i_][j_], 0, 0, 0);
#define BARS                                                                   \
    __builtin_amdgcn_s_barrier();                                              \
    asm volatile("s_waitcnt lgkmcnt(0)" ::: "memory");                         \
    __builtin_amdgcn_sched_barrier(0);                                         \
    __builtin_amdgcn_s_setprio(1);
#define BARE                                                                   \
    __builtin_amdgcn_s_setprio(0);                                             \
    __builtin_amdgcn_sched_barrier(0);                                         \
    __builtin_amdgcn_s_barrier();

    // prologue: tile 0 fully staged + Bl(1); tile0 landed (allow Bl(1) in flight)
    STG(0, Ab, 0, 0) STG(0, Ab, 0, 1)
    STG(32768, Bb, 0, 0) STG(32768, Bb, 0, 1)
    STG(32768, Bb, 1, 0)
    asm volatile("s_waitcnt vmcnt(2)" ::: "memory");
    __builtin_amdgcn_s_barrier();

#pragma unroll 1
    for (int I = 0; I < NI; ++I) {
        int a = 2 * I, b = a + 1;
        bf16x8 af[4], bfr[4];

        // ---- phases 0-3: tile a ----
        RDA(af, a, 0, 0) RDB(bfr, a, 0)
        STG(0, Ab, b, 0)                       // Al(b)
        BARS MM16(0, af, bfr) BARE             // ph0

        RDA(af, a, 4, 0)
        STG(32768, Bb, b, 1)                   // Bh(b)
        BARS MM16(4, af, bfr) BARE             // ph1

        RDA(af, a, 0, 1) RDB(bfr, a, 1)
        STG(0, Ab, b, 1)                       // Ah(b)
        BARS MM16(0, af, bfr) BARE             // ph2

        RDA(af, a, 4, 1)
        if (a + 2 < NT) STG(32768, Bb, a + 2, 0)  // Bl(a+2)
        if (I == NI - 1) { asm volatile("s_waitcnt vmcnt(0)" ::: "memory"); }
        else             { asm volatile("s_waitcnt vmcnt(2)" ::: "memory"); }
        BARS MM16(4, af, bfr) BARE             // ph3

        // ---- phases 4-7: tile b ----
        RDA(af, b, 0, 0) RDB(bfr, b, 0)
        if (a + 2 < NT) STG(0, Ab, a + 2, 0)   // Al(a+2)
        BARS MM16(0, af, bfr) BARE             // ph4

        RDA(af, b, 4, 0)
        if (a + 2 < NT) STG(32768, Bb, a + 2, 1)  // Bh(a+2)
        BARS MM16(4, af, bfr) BARE             // ph5

        RDA(af, b, 0, 1) RDB(bfr, b, 1)
        if (a + 2 < NT) STG(0, Ab, a + 2, 1)   // Ah(a+2)
        BARS MM16(0, af, bfr) BARE             // ph6

        RDA(af, b, 4, 1)
        if (b + 2 < NT) STG(32768, Bb, b + 2, 0)  // Bl(b+2)
        if (I < NI - 1) { asm volatile("s_waitcnt vmcnt(2)" ::: "memory"); }
        BARS MM16(4, af, bfr) BARE             // ph7
    }
#undef STG
#undef RDA
#undef RDB
#undef MM16
#undef BARS
#undef BARE
}

// GEMM1: H[e] = relu(Xd[e] @ W1[e]) -> bf16. 1-D grid, XCD-chunk swizzle.
__global__ __launch_bounds__(512, 1) void gemm1_kernel(
    const unsigned short* __restrict__ Xd, const unsigned short* __restrict__ W1T,
    unsigned short* __restrict__ H)
{
    __shared__ unsigned short sm[65536];   // 128 KiB
    // grid = 512 = (NF/256=16) x (CAP/256=4) x NE; chunk of 64 = one expert slice
    int vid = ((int)blockIdx.x & 7) * 64 + ((int)blockIdx.x >> 3);
    int xb = vid & 15, yb = (vid >> 4) & 3, e = vid >> 6;
    const unsigned short* Ab = Xd + ((size_t)e * CAP + yb * 256) * DM;
    const unsigned short* Bb = W1T + ((size_t)e * NF + xb * 256) * DM;
    f32x4 acc[8][4];
    gemm_core8p<DM, DM>(Ab, Bb, sm, acc);
    __builtin_amdgcn_s_barrier();

    int tid = threadIdx.x, wave = tid >> 6, lane = tid & 63;
    int wc = (wave & 3) * 64;
    size_t Hrow0 = ((size_t)e * CAP + yb * 256) * NF + xb * 256;
    unsigned short* buf = sm;   // 128 rows x 264 cols (padded) = 67.6KB
#pragma unroll
    for (int p = 0; p < 2; ++p) {
        if ((wave >> 2) == p) {
#pragma unroll
            for (int i = 0; i < 8; ++i) {
#pragma unroll
                for (int j = 0; j < 4; ++j) {
                    int col = wc + j * 16 + (lane & 15);
#pragma unroll
                    for (int f = 0; f < 4; ++f) {
                        int lr = i * 16 + (lane >> 4) * 4 + f;
                        float v = acc[i][j][f];
                        v = v > 0.f ? v : 0.f;
                        buf[lr * 264 + col] = f2bf(v);
                    }
                }
            }
        }
        __syncthreads();
#pragma unroll
        for (int v = 0; v < 8; ++v) {
            int sidx = tid + v * 512;
            int r = sidx >> 5, seg = sidx & 31;
            us8v o = *(const us8v*)(buf + r * 264 + seg * 8);
            *(us8v*)(H + Hrow0 + (size_t)(p * 128 + r) * NF + seg * 8) = o;
        }
        __syncthreads();
    }
}

// GEMM2: EO[e] = H[e] @ W2[e]; split-K x2; gate-scale + atomic scatter.
__global__ __launch_bounds__(512, 1) void gemm2_kernel(
    const unsigned short* __restrict__ H, const unsigned short* __restrict__ W2T,
    const int* __restrict__ slot_token, const float* __restrict__ gatev,
    float* __restrict__ out)
{
    __shared__ unsigned short sm[65536];   // 128 KiB
    // grid = 256 = (nb=4) x (ks=2) x (yb=4) x NE; chunk of 32 = one expert slice
    int vid = ((int)blockIdx.x & 7) * 32 + ((int)blockIdx.x >> 3);
    int nb = vid & 3, ks = (vid >> 2) & 1, yb = (vid >> 3) & 3, e = vid >> 5;
    const unsigned short* Ab = H + ((size_t)e * CAP + yb * 256) * NF + ks * (NF / 2);
    const unsigned short* Bb = W2T + ((size_t)e * DM + nb * 256) * NF + ks * (NF / 2);
    f32x4 acc[8][4];
    gemm_core8p<NF / 2, NF>(Ab, Bb, sm, acc);

    int tid = threadIdx.x, wave = tid >> 6, lane = tid & 63;
    int wr = (wave >> 2) * 128;
    int wc = (wave & 3) * 64;
    int slot0 = e * CAP + yb * 256;
    int colbase = nb * 256 + wc + (lane & 15);
#pragma unroll
    for (int i = 0; i < 8; ++i) {
        int rbase = wr + i * 16 + (lane >> 4) * 4;
#pragma unroll
        for (int f = 0; f < 4; ++f) {
            int row = rbase + f;
            int t = slot_token[slot0 + row];
            if (t >= 0) {
                float g = gatev[t];
#pragma unroll
                for (int j = 0; j < 4; ++j) {
                    unsafeAtomicAdd(&out[(size_t)t * DM + colbase + j * 16], acc[i][j][f] * g);
                }
            }
        }
    }
}

extern "C" void kernel_launch(void* const* d_in, const int* in_sizes, int n_in,
                              void* d_out, int out_size, void* d_ws, size_t ws_size,
                              hipStream_t stream)
{
    const float* x  = (const float*)d_in[0];
    const float* wg = (const float*)d_in[1];
    const float* w1 = (const float*)d_in[2];
    const float* w2 = (const float*)d_in[3];
    float* out = (float*)d_out;

    char* ws = (char*)d_ws;
    size_t o = 0;
    auto nxt = [&](size_t b) { size_t r = o; o += (b + 255) & ~(size_t)255; return r; };
    int*   eid        = (int*)  (ws + nxt((size_t)NTOK * 4));
    float* gatev      = (float*)(ws + nxt((size_t)NTOK * 4));
    int*   slot_token = (int*)  (ws + nxt((size_t)NTOK * 4));
    unsigned short* Xd = (unsigned short*)(ws + nxt((size_t)NTOK * DM * 2));
    unsigned short* WT = (unsigned short*)(ws + nxt((size_t)NE * NF * DM * 2)); // W1T then W2T (aliased)
    unsigned short* Hb = (unsigned short*)(ws + nxt((size_t)NE * CAP * NF * 2));

    gate_kernel<<<NTOK / 4, 256, 0, stream>>>(x, wg, eid, gatev);
    scan_kernel<<<1, 1024, 0, stream>>>(eid, slot_token);
    convT_kernel<DM, NF><<<dim3(NF / 64, DM / 64, NE), 256, 0, stream>>>(w1, WT);
    gather_kernel<<<NTOK / 2, 256, 0, stream>>>(x, slot_token, Xd);
    gemm1_kernel<<<dim3(512), 512, 0, stream>>>(Xd, WT, Hb);
    convT_kernel<NF, DM><<<dim3(DM / 64, NF / 64, NE), 256, 0, stream>>>(w2, WT);
    hipMemsetAsync(d_out, 0, (size_t)out_size * sizeof(float), stream);
    gemm2_kernel<<<dim3(256), 512, 0, stream>>>(Hb, WT, slot_token, gatev, out);
}